// Round 1
// baseline (961.279 us; speedup 1.0000x reference)
//
#include <hip/hip_runtime.h>

// Problem: VertexUpdate — segment_sum of edge_attr[:,1] over edge source
// indices, then out = concat([b, x, b - cbar], axis=1) per vertex.
// Inputs: vertex_attr (1e6,2) f32, edgeij_pair (2,16e6) int (row 0 = src),
// edge_attr (16e6,2) f32, g (unused), batch (unused).
// Output: (1e6,3) f32 row-major.

__global__ void vu_init_kernel(const float* __restrict__ vattr,
                               float* __restrict__ out, int n) {
    int i = blockIdx.x * blockDim.x + threadIdx.x;
    if (i < n) {
        float2 v = ((const float2*)vattr)[i];  // v.x = b_i, v.y = x_i
        out[3 * i + 0] = v.x;
        out[3 * i + 1] = v.y;
        out[3 * i + 2] = v.x;  // r_i starts at b_i; scatter subtracts c_ij
    }
}

__global__ void vu_scatter_kernel(const int* __restrict__ src,
                                  const float* __restrict__ eattr,
                                  float* __restrict__ out, int ne) {
    int t = blockIdx.x * blockDim.x + threadIdx.x;
    int e0 = t * 4;
    if (e0 + 3 < ne) {
        int4 idx = ((const int4*)src)[t];
        // edge_attr rows (e0..e0+3): two float4 = 4 edges * (b_ij, c_ij)
        float4 a = ((const float4*)eattr)[2 * t + 0];  // e0:(x,y) e0+1:(z,w)
        float4 b = ((const float4*)eattr)[2 * t + 1];  // e0+2, e0+3
        atomicAdd(&out[3 * idx.x + 2], -a.y);
        atomicAdd(&out[3 * idx.y + 2], -a.w);
        atomicAdd(&out[3 * idx.z + 2], -b.y);
        atomicAdd(&out[3 * idx.w + 2], -b.w);
    } else {
        for (int e = e0; e < ne; ++e) {
            atomicAdd(&out[3 * src[e] + 2], -eattr[2 * e + 1]);
        }
    }
}

extern "C" void kernel_launch(void* const* d_in, const int* in_sizes, int n_in,
                              void* d_out, int out_size, void* d_ws, size_t ws_size,
                              hipStream_t stream) {
    const float* vattr = (const float*)d_in[0];
    const int* edges = (const int*)d_in[1];   // (2, N_E); row 0 = src
    const float* eattr = (const float*)d_in[2];
    float* out = (float*)d_out;

    int nv = in_sizes[0] / 2;   // 1,000,000
    int ne = in_sizes[2] / 2;   // 16,000,000

    // 1) initialize out: b, x, and r := b
    {
        int threads = 256;
        int blocks = (nv + threads - 1) / threads;
        vu_init_kernel<<<blocks, threads, 0, stream>>>(vattr, out, nv);
    }
    // 2) scatter-subtract c_ij into r slot (4 edges/thread, vectorized loads)
    {
        int threads = 256;
        int nt = (ne + 3) / 4;
        int blocks = (nt + threads - 1) / threads;
        vu_scatter_kernel<<<blocks, threads, 0, stream>>>(edges, eattr, out, ne);
    }
}